// Round 4
// baseline (103.830 us; speedup 1.0000x reference)
//
#include <hip/hip_runtime.h>

typedef __attribute__((ext_vector_type(8))) short bf16x8;
typedef __attribute__((ext_vector_type(4))) float f32x4;

__device__ __forceinline__ unsigned int f2bf(float f) {
    union { float f; unsigned int u; } v; v.f = f;
    unsigned int u = v.u;
    u += 0x7FFFu + ((u >> 16) & 1u);   // round-to-nearest-even
    return u >> 16;
}

// Pack lin1_W [256][256] f32 (row-major, W[k][n]) into bf16 MFMA-B-fragment order,
// F-MAJOR: 16B unit index tid = (f*8 + kt)*64 + lane holds
//   { W[kt*32 + (lane>>4)*8 + j][f*16 + (lane&15)] : j = 0..7 }
// => slab f is a contiguous 8 KiB block: perfect for LDS staging.
__global__ void pack_w_kernel(const float* __restrict__ W, unsigned short* __restrict__ P) {
    int tid = blockIdx.x * blockDim.x + threadIdx.x;
    if (tid >= 8192) return;
    int f    = tid >> 9;
    int kt   = (tid >> 6) & 7;
    int lane = tid & 63;
    int k0  = kt * 32 + (lane >> 4) * 8;
    int col = f * 16 + (lane & 15);
    bf16x8 v;
    #pragma unroll
    for (int j = 0; j < 8; ++j)
        v[j] = (short)f2bf(W[(k0 + j) * 256 + col]);
    ((bf16x8*)P)[tid] = v;
}

__global__ __launch_bounds__(256, 2)
void fused_kernel(const float* __restrict__ x,
                  const int* __restrict__ samples,
                  const unsigned short* __restrict__ Wp,
                  const float* __restrict__ b1,
                  const float* __restrict__ w2,
                  const float* __restrict__ b2,
                  float* __restrict__ out, int S)
{
    // 128-row z tile, unpadded bf16, XOR-swizzled (byte ^= (row&7)<<4): 64 KiB
    __shared__ unsigned short zt[128 * 256];
    // W f-slab double buffer: 2 x 8 KiB (slab f = 512 x 16B fragment units)
    __shared__ unsigned short wbuf[2][4096];
    // total 80 KiB -> exactly 2 blocks/CU

    const int tid  = threadIdx.x;
    const int lane = tid & 63;
    const int wave = tid >> 6;
    const int cl   = lane & 15;
    const int hi   = lane >> 4;
    const int row0 = blockIdx.x * 128 + wave * 32;   // this wave's first output row

    const bf16x8* wpv = (const bf16x8*)Wp;

    // ---- prologue: issue slab-0 W loads early (latency hides under gathers) ----
    bf16x8 w0a = wpv[tid];
    bf16x8 w0b = wpv[256 + tid];

    // ---- this wave's 64 sample indices (32 rows), one coalesced load ----
    int imax = 2 * S - 1;
    int i0   = row0 * 2 + lane;
    int sidx = samples[i0 < imax ? i0 : imax];

    // ---- gather + mul + bf16 pack into swizzled zt; 16 loads in flight/batch ----
    char* ztb = (char*)zt;
    #pragma unroll
    for (int g = 0; g < 4; ++g) {
        f32x4 va[8], vb[8];
        #pragma unroll
        for (int r = 0; r < 8; ++r) {
            int rr = g * 8 + r;
            int a  = __shfl(sidx, rr * 2,     64);
            int b  = __shfl(sidx, rr * 2 + 1, 64);
            va[r] = ((const f32x4*)x)[(size_t)a * 64 + lane];
            vb[r] = ((const f32x4*)x)[(size_t)b * 64 + lane];
        }
        #pragma unroll
        for (int r = 0; r < 8; ++r) {
            int rr = g * 8 + r;
            uint2 u;
            u.x = f2bf(va[r][0] * vb[r][0]) | (f2bf(va[r][1] * vb[r][1]) << 16);
            u.y = f2bf(va[r][2] * vb[r][2]) | (f2bf(va[r][3] * vb[r][3]) << 16);
            int brow = wave * 32 + rr;
            int off  = (brow * 512 + lane * 8) ^ ((brow & 7) << 4);
            *(uint2*)(ztb + off) = u;
        }
    }

    // ---- stage slab 0 into wbuf[0] ----
    {
        bf16x8* wv = (bf16x8*)wbuf[0];
        wv[tid]       = w0a;
        wv[tid + 256] = w0b;
    }
    __syncthreads();

    // ---- hoist A-fragments: af[rt][kt] = z[row0 + rt*16 + cl][kt*32 + hi*8 ..+8] ----
    bf16x8 af[2][8];
    #pragma unroll
    for (int rt = 0; rt < 2; ++rt) {
        int brow = wave * 32 + rt * 16 + cl;
        #pragma unroll
        for (int kt = 0; kt < 8; ++kt) {
            int off = (brow * 512 + kt * 64 + hi * 16) ^ ((brow & 7) << 4);
            af[rt][kt] = *(const bf16x8*)(ztb + off);
        }
    }

    // ---- f-major loop: slab f from LDS, prefetch slab f+1, fused epilogue ----
    float p0[2][4] = {{0.f,0.f,0.f,0.f},{0.f,0.f,0.f,0.f}};
    float p1[2][4] = {{0.f,0.f,0.f,0.f},{0.f,0.f,0.f,0.f}};

    for (int f = 0; f < 16; ++f) {
        bf16x8 r0, r1;
        if (f < 15) {                       // issue next-slab loads FIRST
            r0 = wpv[(f + 1) * 512 + tid];
            r1 = wpv[(f + 1) * 512 + 256 + tid];
        }
        const bf16x8* bcv = (const bf16x8*)wbuf[f & 1];
        bf16x8 bc[8];
        #pragma unroll
        for (int kt = 0; kt < 8; ++kt) bc[kt] = bcv[kt * 64 + lane];

        f32x4 a0 = (f32x4){0.f,0.f,0.f,0.f};
        f32x4 a1 = (f32x4){0.f,0.f,0.f,0.f};
        #pragma unroll
        for (int kt = 0; kt < 8; ++kt) {
            a0 = __builtin_amdgcn_mfma_f32_16x16x32_bf16(af[0][kt], bc[kt], a0, 0, 0, 0);
            a1 = __builtin_amdgcn_mfma_f32_16x16x32_bf16(af[1][kt], bc[kt], a1, 0, 0, 0);
        }

        float  b1v = b1[f * 16 + cl];
        float2 lw  = ((const float2*)w2)[f * 16 + cl];
        #pragma unroll
        for (int q = 0; q < 4; ++q) {
            float h0 = fmaxf(a0[q] + b1v, 0.f);
            float h1 = fmaxf(a1[q] + b1v, 0.f);
            p0[0][q] += h0 * lw.x;  p1[0][q] += h0 * lw.y;
            p0[1][q] += h1 * lw.x;  p1[1][q] += h1 * lw.y;
        }

        if (f < 15) {                       // write next slab late (T14)
            bf16x8* wv = (bf16x8*)wbuf[(f + 1) & 1];
            wv[tid]       = r0;
            wv[tid + 256] = r1;
        }
        __syncthreads();
    }

    // ---- 16-lane shuffle reduce + store, per row-tile ----
    #pragma unroll
    for (int rt = 0; rt < 2; ++rt) {
        #pragma unroll
        for (int m = 1; m < 16; m <<= 1) {
            #pragma unroll
            for (int q = 0; q < 4; ++q) {
                p0[rt][q] += __shfl_xor(p0[rt][q], m, 64);
                p1[rt][q] += __shfl_xor(p1[rt][q], m, 64);
            }
        }
        if (cl < 8) {
            int q = cl >> 1, j = cl & 1;
            int r = row0 + rt * 16 + hi * 4 + q;
            if (r < S) {
                float v = (j == 0 ? p0[rt][q] : p1[rt][q]) + b2[j];
                out[r * 2 + j] = v;
            }
        }
    }
}

extern "C" void kernel_launch(void* const* d_in, const int* in_sizes, int n_in,
                              void* d_out, int out_size, void* d_ws, size_t ws_size,
                              hipStream_t stream) {
    // setup_inputs order:
    // 0 x_feature, 1 edge_index(unused), 2 samples, 3 W1(u), 4 b1(u), 5 W2(u), 6 b2(u),
    // 7 lin1_W, 8 lin1_b, 9 lin2_W, 10 lin2_b
    const float* x       = (const float*)d_in[0];
    const int*   samples = (const int*)d_in[2];
    const float* lin1_W  = (const float*)d_in[7];
    const float* lin1_b  = (const float*)d_in[8];
    const float* lin2_W  = (const float*)d_in[9];
    const float* lin2_b  = (const float*)d_in[10];
    float* out = (float*)d_out;

    unsigned short* Wp = (unsigned short*)d_ws;   // 8192 * 16B = 128 KiB packed lin1_W
    const int S = in_sizes[2] / 2;                // 100000 sample pairs

    pack_w_kernel<<<32, 256, 0, stream>>>(lin1_W, Wp);

    const int nblk = (S + 127) / 128;             // 782 blocks of 128 rows
    fused_kernel<<<nblk, 256, 0, stream>>>(x, samples, Wp, lin1_b, lin2_W, lin2_b, out, S);
}

// Round 5
// 85.377 us; speedup vs baseline: 1.2161x; 1.2161x over previous
//
#include <hip/hip_runtime.h>

typedef __attribute__((ext_vector_type(8))) short bf16x8;
typedef __attribute__((ext_vector_type(4))) float f32x4;

__device__ __forceinline__ unsigned int f2bf(float f) {
    union { float f; unsigned int u; } v; v.f = f;
    unsigned int u = v.u;
    u += 0x7FFFu + ((u >> 16) & 1u);   // round-to-nearest-even
    return u >> 16;
}

// Pack lin1_W [256][256] f32 (row-major, W[k][n]) into bf16 MFMA-B-fragment order,
// F-MAJOR: 16B unit index tid = (f*8 + kt)*64 + lane holds
//   { W[kt*32 + (lane>>4)*8 + j][f*16 + (lane&15)] : j = 0..7 }
// => slab f is a contiguous 8 KiB block; chunk c = slabs {2c,2c+1} = 16 KiB.
__global__ void pack_w_kernel(const float* __restrict__ W, unsigned short* __restrict__ P) {
    int tid = blockIdx.x * blockDim.x + threadIdx.x;
    if (tid >= 8192) return;
    int f    = tid >> 9;
    int kt   = (tid >> 6) & 7;
    int lane = tid & 63;
    int k0  = kt * 32 + (lane >> 4) * 8;
    int col = f * 16 + (lane & 15);
    bf16x8 v;
    #pragma unroll
    for (int j = 0; j < 8; ++j)
        v[j] = (short)f2bf(W[(k0 + j) * 256 + col]);
    ((bf16x8*)P)[tid] = v;
}

__global__ __launch_bounds__(256, 4)
void fused_kernel(const float* __restrict__ x,
                  const int* __restrict__ samples,
                  const unsigned short* __restrict__ Wp,
                  const float* __restrict__ b1,
                  const float* __restrict__ w2,
                  const float* __restrict__ b2,
                  float* __restrict__ out, int S)
{
    // ONLY LDS: W chunk double-buffer, 2 x 16 KiB -> 4+ blocks/CU
    __shared__ bf16x8 wbuf[2][1024];

    const int tid  = threadIdx.x;
    const int lane = tid & 63;
    const int wave = tid >> 6;
    const int cl   = lane & 15;
    const int hi   = lane >> 4;
    const int row0 = blockIdx.x * 64 + wave * 16;   // this wave's first output row

    const bf16x8* wpv = (const bf16x8*)Wp;

    // ---- issue chunk-0 W loads first: latency hides under the gather phase ----
    bf16x8 st[4];
    #pragma unroll
    for (int i = 0; i < 4; ++i) st[i] = wpv[i * 256 + tid];

    // ---- sample indices: one coalesced load, distribute via shfl ----
    int imax = 2 * S - 1;
    int i0   = row0 * 2 + (lane & 31);
    int sidx = samples[i0 < imax ? i0 : imax];
    int ra = __shfl(sidx, 2 * cl,     64);
    int rb = __shfl(sidx, 2 * cl + 1, 64);
    const f32x4* xa = (const f32x4*)x + (size_t)ra * 64;
    const f32x4* xb = (const f32x4*)x + (size_t)rb * 64;

    // ---- direct per-lane A-fragment gather: 32 independent 16B loads in flight ----
    // af[kt][j] = bf16( x[ra][kt*32+hi*8+j] * x[rb][kt*32+hi*8+j] ), j=0..7
    bf16x8 af[8];
    {
        f32x4 va[8][2], vb[8][2];
        #pragma unroll
        for (int kt = 0; kt < 8; ++kt) {
            int o = kt * 8 + hi * 2;          // f32x4-unit offset of k = kt*32 + hi*8
            va[kt][0] = xa[o];  va[kt][1] = xa[o + 1];
            vb[kt][0] = xb[o];  vb[kt][1] = xb[o + 1];
        }
        #pragma unroll
        for (int kt = 0; kt < 8; ++kt) {
            bf16x8 v;
            #pragma unroll
            for (int j = 0; j < 4; ++j) {
                v[j]     = (short)f2bf(va[kt][0][j] * vb[kt][0][j]);
                v[4 + j] = (short)f2bf(va[kt][1][j] * vb[kt][1][j]);
            }
            af[kt] = v;
        }
    }

    // ---- stage chunk 0 ----
    #pragma unroll
    for (int i = 0; i < 4; ++i) wbuf[0][i * 256 + tid] = st[i];
    __syncthreads();

    float p0[4] = {0.f, 0.f, 0.f, 0.f};
    float p1[4] = {0.f, 0.f, 0.f, 0.f};

    // ---- 8 chunks x 2 f-slabs; issue loads early, write late, 1 barrier/chunk ----
    for (int c = 0; c < 8; ++c) {
        if (c < 7) {
            #pragma unroll
            for (int i = 0; i < 4; ++i) st[i] = wpv[(c + 1) * 1024 + i * 256 + tid];
        }
        const bf16x8* cb = wbuf[c & 1];
        #pragma unroll
        for (int s = 0; s < 2; ++s) {
            int f = 2 * c + s;
            bf16x8 bc[8];
            #pragma unroll
            for (int kt = 0; kt < 8; ++kt) bc[kt] = cb[s * 512 + kt * 64 + lane];
            f32x4 a4 = (f32x4){0.f, 0.f, 0.f, 0.f};
            #pragma unroll
            for (int kt = 0; kt < 8; ++kt)
                a4 = __builtin_amdgcn_mfma_f32_16x16x32_bf16(af[kt], bc[kt], a4, 0, 0, 0);
            float  b1v = b1[f * 16 + cl];
            float2 lw  = ((const float2*)w2)[f * 16 + cl];
            #pragma unroll
            for (int q = 0; q < 4; ++q) {
                float h = fmaxf(a4[q] + b1v, 0.f);
                p0[q] += h * lw.x;
                p1[q] += h * lw.y;
            }
        }
        if (c < 7) {
            #pragma unroll
            for (int i = 0; i < 4; ++i) wbuf[(c + 1) & 1][i * 256 + tid] = st[i];
        }
        __syncthreads();
    }

    // ---- 16-lane shuffle reduce of the [16x2] partials + store ----
    #pragma unroll
    for (int m = 1; m < 16; m <<= 1) {
        #pragma unroll
        for (int q = 0; q < 4; ++q) {
            p0[q] += __shfl_xor(p0[q], m, 64);
            p1[q] += __shfl_xor(p1[q], m, 64);
        }
    }
    // lanes cl=0..7 of each 16-lane group write 8 consecutive floats (4 rows x 2 cols)
    if (cl < 8) {
        int q = cl >> 1, j = cl & 1;
        int r = row0 + hi * 4 + q;
        if (r < S) {
            float v = (j == 0 ? p0[q] : p1[q]) + b2[j];
            out[r * 2 + j] = v;
        }
    }
}

extern "C" void kernel_launch(void* const* d_in, const int* in_sizes, int n_in,
                              void* d_out, int out_size, void* d_ws, size_t ws_size,
                              hipStream_t stream) {
    // setup_inputs order:
    // 0 x_feature, 1 edge_index(unused), 2 samples, 3 W1(u), 4 b1(u), 5 W2(u), 6 b2(u),
    // 7 lin1_W, 8 lin1_b, 9 lin2_W, 10 lin2_b
    const float* x       = (const float*)d_in[0];
    const int*   samples = (const int*)d_in[2];
    const float* lin1_W  = (const float*)d_in[7];
    const float* lin1_b  = (const float*)d_in[8];
    const float* lin2_W  = (const float*)d_in[9];
    const float* lin2_b  = (const float*)d_in[10];
    float* out = (float*)d_out;

    unsigned short* Wp = (unsigned short*)d_ws;   // 8192 * 16B = 128 KiB packed lin1_W
    const int S = in_sizes[2] / 2;                // 100000 sample pairs

    pack_w_kernel<<<32, 256, 0, stream>>>(lin1_W, Wp);

    const int nblk = (S + 63) / 64;               // 1563 blocks of 64 rows
    fused_kernel<<<nblk, 256, 0, stream>>>(x, samples, Wp, lin1_b, lin2_W, lin2_b, out, S);
}